// Round 4
// baseline (887.325 us; speedup 1.0000x reference)
//
#include <hip/hip_runtime.h>

#define HD  128   // hidden dim
#define TM  64    // node rows per block in the GIN layer kernel
#define SYB 136   // bf16 LDS stride for Y tiles (272 B row: 16B-aligned, 2-way bank max)

typedef __attribute__((ext_vector_type(8))) short short8;
typedef __attribute__((ext_vector_type(4))) float float4v;

// split fp32 -> bf16 hi + bf16 lo (RNE both), v == hi + lo to ~2^-17 rel
__device__ __forceinline__ void split_bf(float v, short& hi, short& lo) {
    unsigned bv = __float_as_uint(v);
    unsigned hb = (bv + 0x7FFFu + ((bv >> 16) & 1u)) & 0xFFFF0000u;
    hi = (short)(hb >> 16);
    float r = v - __uint_as_float(hb);
    unsigned rv = __float_as_uint(r);
    lo = (short)((rv + 0x7FFFu + ((rv >> 16) & 1u)) >> 16);
}

// ---------------------------------------------------------------- embed ----
__global__ void k_embed(const int* __restrict__ tok, const float* __restrict__ emb,
                        float* __restrict__ x, int n)
{
    int g = blockIdx.x * 256 + threadIdx.x;          // one float4 per thread
    if (g < n * 32) {
        int node = g >> 5, part = g & 31;
        ((float4*)x)[g] = ((const float4*)emb)[(tok[node] << 5) + part];
    }
}

// ------------------------------------------------------------- CSR build ----
__global__ void k_degree(const int* __restrict__ dst, int* __restrict__ deg, int e)
{
    int i = blockIdx.x * 256 + threadIdx.x;
    if (i < e) atomicAdd(&deg[dst[i]], 1);
}

__global__ void k_scan1(const int* __restrict__ deg, int* __restrict__ rp,
                        int* __restrict__ bsum, int n)
{
    __shared__ int s[1024];
    int t = threadIdx.x;
    int i = blockIdx.x * 1024 + t;
    int v = (i < n) ? deg[i] : 0;
    s[t] = v; __syncthreads();
    for (int off = 1; off < 1024; off <<= 1) {
        int tmp = (t >= off) ? s[t - off] : 0;
        __syncthreads();
        s[t] += tmp;
        __syncthreads();
    }
    if (i < n) rp[i] = s[t] - v;                 // exclusive
    if (t == 1023) bsum[blockIdx.x] = s[1023];
}

__global__ void k_scan2(int* __restrict__ bsum, int nb)
{
    __shared__ int s[128];
    int t = threadIdx.x;
    int v = (t < nb) ? bsum[t] : 0;
    s[t] = v; __syncthreads();
    for (int off = 1; off < 128; off <<= 1) {
        int tmp = (t >= off) ? s[t - off] : 0;
        __syncthreads();
        s[t] += tmp;
        __syncthreads();
    }
    if (t < nb) bsum[t] = s[t] - v;              // exclusive block offsets
}

__global__ void k_scan3(int* __restrict__ rp, const int* __restrict__ bsum, int n, int e)
{
    int i = blockIdx.x * 1024 + threadIdx.x;
    if (i < n) rp[i] += bsum[blockIdx.x];
    if (i == 0) rp[n] = e;
}

__global__ void k_fill(const int* __restrict__ src, const int* __restrict__ dst,
                       const int* __restrict__ rp, int* __restrict__ fill,
                       int* __restrict__ ci, int e)
{
    int i = blockIdx.x * 256 + threadIdx.x;
    if (i < e) {
        int d = dst[i];
        int p = atomicAdd(&fill[d], 1);
        ci[rp[d] + p] = src[i];
    }
}

// --------------------------------------------- weight split into B-frags ----
// Output layout per (layer, matrix): frag idx f = ((ct*4 + kb)*64 + lane)*8 + j
// holds W[kb*32 + (lane>>4)*8 + j][ct*16 + (lane&15)]  (B-operand of 16x16x32)
__global__ void k_wsplit(const float* __restrict__ W1, const float* __restrict__ W2,
                         short* __restrict__ wh, short* __restrict__ wl, int total)
{
    int g = blockIdx.x * 256 + threadIdx.x;
    if (g >= total) return;
    int f  = g & 16383;
    int m  = (g >> 14) & 1;
    int l  = g >> 15;
    int j    = f & 7;
    int lane = (f >> 3) & 63;
    int kb   = (f >> 9) & 3;
    int ct   = f >> 11;
    int k  = kb * 32 + (lane >> 4) * 8 + j;
    int nn = ct * 16 + (lane & 15);
    const float* W = m ? W2 : W1;
    float v = W[(size_t)l * 16384 + k * 128 + nn];
    short h, lo; split_bf(v, h, lo);
    wh[g] = h; wl[g] = lo;
}

// ------------------------------------------------------------- GIN layer ----
__global__ __launch_bounds__(256, 4)
void k_gin(const float* __restrict__ xin, float* __restrict__ xout,
           const int* __restrict__ rp, const int* __restrict__ ci,
           const short* __restrict__ w1h, const short* __restrict__ w1l,
           const short* __restrict__ w2h, const short* __restrict__ w2l,
           const float* __restrict__ b1, const float* __restrict__ b2,
           int n)
{
    __shared__ short sYh[TM * SYB];
    __shared__ short sYl[TM * SYB];
    __shared__ float sBias[2 * HD];

    const int tx   = threadIdx.x;
    const int row0 = blockIdx.x * TM;
    const int wv   = tx >> 6, lane = tx & 63;
    const int quad = lane >> 4, lrow = lane & 15;

    if (tx < 128) { sBias[tx] = b1[tx]; sBias[128 + tx] = b2[tx]; }

    // prefetch this wave's GEMM1 B-fragments (cols [32*wv, 32*wv+32))
    short8 B1h[2][4], B1l[2][4];
    {
        const short8* h8 = (const short8*)w1h;
        const short8* l8 = (const short8*)w1l;
#pragma unroll
        for (int c = 0; c < 2; ++c)
#pragma unroll
            for (int kb = 0; kb < 4; ++kb) {
                int idx = ((2 * wv + c) * 4 + kb) * 64 + lane;
                B1h[c][kb] = h8[idx];
                B1l[c][kb] = l8[idx];
            }
    }

    // ---- aggregation: Y[row] = x[row] + sum_{j in CSR[row]} x[j], split to bf16 hi/lo LDS
    {
        const int rl = tx >> 2, part = tx & 3;   // 4 threads per row, 32 floats each
        const int node = row0 + rl;
        const int j0 = part * 32;
        float4 acc[8];
        if (node < n) {
            const float4* xr = (const float4*)(xin + (size_t)node * HD + j0);
#pragma unroll
            for (int q = 0; q < 8; ++q) acc[q] = xr[q];
            int e = rp[node];
            const int e1 = rp[node + 1];
            // unroll-2: pair ci loads to break the ci->gather chain; 16 float4 in flight
            for (; e + 2 <= e1; e += 2) {
                int c0 = ci[e], c1 = ci[e + 1];
                const float4* x0 = (const float4*)(xin + (size_t)c0 * HD + j0);
                const float4* x1 = (const float4*)(xin + (size_t)c1 * HD + j0);
                float4 v0[8], v1[8];
#pragma unroll
                for (int q = 0; q < 8; ++q) v0[q] = x0[q];
#pragma unroll
                for (int q = 0; q < 8; ++q) v1[q] = x1[q];
#pragma unroll
                for (int q = 0; q < 8; ++q) {
                    acc[q].x += v0[q].x + v1[q].x;
                    acc[q].y += v0[q].y + v1[q].y;
                    acc[q].z += v0[q].z + v1[q].z;
                    acc[q].w += v0[q].w + v1[q].w;
                }
            }
            if (e < e1) {
                const float4* xc = (const float4*)(xin + (size_t)ci[e] * HD + j0);
#pragma unroll
                for (int q = 0; q < 8; ++q) {
                    float4 v = xc[q];
                    acc[q].x += v.x; acc[q].y += v.y; acc[q].z += v.z; acc[q].w += v.w;
                }
            }
        } else {
#pragma unroll
            for (int q = 0; q < 8; ++q) acc[q] = make_float4(0.f, 0.f, 0.f, 0.f);
        }
        short* yh = &sYh[rl * SYB + j0];
        short* yl = &sYl[rl * SYB + j0];
#pragma unroll
        for (int q = 0; q < 8; ++q) {
            short h0, l0, h1, l1, h2, l2, h3, l3;
            split_bf(acc[q].x, h0, l0);
            split_bf(acc[q].y, h1, l1);
            split_bf(acc[q].z, h2, l2);
            split_bf(acc[q].w, h3, l3);
            *(short4*)(yh + q * 4) = make_short4(h0, h1, h2, h3);
            *(short4*)(yl + q * 4) = make_short4(l0, l1, l2, l3);
        }
    }
    __syncthreads();

    // ---- GEMM1: H = relu(Y @ W1 + b1); wave handles rows 0..63 x cols [32wv,32wv+32)
    float4v acc1[4][2];
#pragma unroll
    for (int rt = 0; rt < 4; ++rt)
#pragma unroll
        for (int c = 0; c < 2; ++c) {
            float bb = sBias[(2 * wv + c) * 16 + lrow];
            acc1[rt][c] = (float4v){bb, bb, bb, bb};
        }

#pragma unroll
    for (int kb = 0; kb < 4; ++kb) {
        short8 Ah[4], Al[4];
#pragma unroll
        for (int rt = 0; rt < 4; ++rt) {
            int off = (rt * 16 + lrow) * SYB + kb * 32 + quad * 8;
            Ah[rt] = *(const short8*)&sYh[off];
            Al[rt] = *(const short8*)&sYl[off];
        }
#pragma unroll
        for (int c = 0; c < 2; ++c)
#pragma unroll
            for (int rt = 0; rt < 4; ++rt) {
                acc1[rt][c] = __builtin_amdgcn_mfma_f32_16x16x32_bf16(Ah[rt], B1h[c][kb], acc1[rt][c], 0, 0, 0);
                acc1[rt][c] = __builtin_amdgcn_mfma_f32_16x16x32_bf16(Al[rt], B1h[c][kb], acc1[rt][c], 0, 0, 0);
                acc1[rt][c] = __builtin_amdgcn_mfma_f32_16x16x32_bf16(Ah[rt], B1l[c][kb], acc1[rt][c], 0, 0, 0);
            }
    }

    __syncthreads();   // all waves done reading Y

    // H (relu) -> split back into sYh/sYl
#pragma unroll
    for (int rt = 0; rt < 4; ++rt)
#pragma unroll
        for (int c = 0; c < 2; ++c) {
            int col = (2 * wv + c) * 16 + lrow;
#pragma unroll
            for (int r = 0; r < 4; ++r) {
                int row = rt * 16 + quad * 4 + r;
                float v = fmaxf(acc1[rt][c][r], 0.f);
                short h, l; split_bf(v, h, l);
                sYh[row * SYB + col] = h;
                sYl[row * SYB + col] = l;
            }
        }

    // GEMM2 B-fragments (L2-hot; latency overlaps epilogue + barrier)
    short8 B2h[2][4], B2l[2][4];
    {
        const short8* h8 = (const short8*)w2h;
        const short8* l8 = (const short8*)w2l;
#pragma unroll
        for (int c = 0; c < 2; ++c)
#pragma unroll
            for (int kb = 0; kb < 4; ++kb) {
                int idx = ((2 * wv + c) * 4 + kb) * 64 + lane;
                B2h[c][kb] = h8[idx];
                B2l[c][kb] = l8[idx];
            }
    }
    __syncthreads();

    // ---- GEMM2: X' = relu(H @ W2 + b2)
    float4v acc2[4][2];
#pragma unroll
    for (int rt = 0; rt < 4; ++rt)
#pragma unroll
        for (int c = 0; c < 2; ++c) {
            float bb = sBias[128 + (2 * wv + c) * 16 + lrow];
            acc2[rt][c] = (float4v){bb, bb, bb, bb};
        }

#pragma unroll
    for (int kb = 0; kb < 4; ++kb) {
        short8 Ah[4], Al[4];
#pragma unroll
        for (int rt = 0; rt < 4; ++rt) {
            int off = (rt * 16 + lrow) * SYB + kb * 32 + quad * 8;
            Ah[rt] = *(const short8*)&sYh[off];
            Al[rt] = *(const short8*)&sYl[off];
        }
#pragma unroll
        for (int c = 0; c < 2; ++c)
#pragma unroll
            for (int rt = 0; rt < 4; ++rt) {
                acc2[rt][c] = __builtin_amdgcn_mfma_f32_16x16x32_bf16(Ah[rt], B2h[c][kb], acc2[rt][c], 0, 0, 0);
                acc2[rt][c] = __builtin_amdgcn_mfma_f32_16x16x32_bf16(Al[rt], B2h[c][kb], acc2[rt][c], 0, 0, 0);
                acc2[rt][c] = __builtin_amdgcn_mfma_f32_16x16x32_bf16(Ah[rt], B2l[c][kb], acc2[rt][c], 0, 0, 0);
            }
    }

    // epilogue: relu + store fp32
#pragma unroll
    for (int rt = 0; rt < 4; ++rt)
#pragma unroll
        for (int c = 0; c < 2; ++c) {
            int col = (2 * wv + c) * 16 + lrow;
#pragma unroll
            for (int r = 0; r < 4; ++r) {
                int node = row0 + rt * 16 + quad * 4 + r;
                if (node < n)
                    xout[(size_t)node * HD + col] = fmaxf(acc2[rt][c][r], 0.f);
            }
        }
}

// ------------------------------------------------------------------ pool ----
__global__ void k_ranges(const int* __restrict__ batch, int* __restrict__ gs,
                         int* __restrict__ ge, int n)
{
    int i = blockIdx.x * 256 + threadIdx.x;
    if (i < n) {
        int b = batch[i];
        if (i == 0 || batch[i - 1] != b) gs[b] = i;
        if (i == n - 1 || batch[i + 1] != b) ge[b] = i + 1;
    }
}

__global__ void k_pool(const float* __restrict__ x, const int* __restrict__ gs,
                       const int* __restrict__ ge, float* __restrict__ out)
{
    int g = blockIdx.x, t = threadIdx.x;   // 128 threads = 1 column each
    int s = gs[g], e = ge[g];
    float sum = 0.f;
    for (int i = s; i < e; ++i) sum += x[(size_t)i * HD + t];
    int cnt = e - s;
    out[(size_t)g * HD + t] = (cnt > 0) ? sum / (float)cnt : 0.f;
}

// ---------------------------------------------------------------- launch ----
extern "C" void kernel_launch(void* const* d_in, const int* in_sizes, int n_in,
                              void* d_out, int out_size, void* d_ws, size_t ws_size,
                              hipStream_t stream)
{
    const int*   tok   = (const int*)d_in[0];
    const int*   eidx  = (const int*)d_in[1];
    const int*   batch = (const int*)d_in[2];
    const float* emb   = (const float*)d_in[3];
    const float* W1    = (const float*)d_in[4];
    const float* b1    = (const float*)d_in[5];
    const float* W2    = (const float*)d_in[6];
    const float* b2    = (const float*)d_in[7];
    float* out = (float*)d_out;

    const int n      = in_sizes[0];
    const int e      = in_sizes[1] / 2;
    const int ngraph = out_size / HD;
    const int L      = in_sizes[4] / (HD * HD);
    const int* src = eidx;
    const int* dst = eidx + e;

    char* w = (char*)d_ws;
    size_t off = 0;
    auto alloc = [&](size_t bytes) -> void* {
        void* p = w + off;
        off = (off + bytes + 255) & ~(size_t)255;
        return p;
    };
    float* xa  = (float*)alloc((size_t)n * HD * 4);
    float* xb  = (float*)alloc((size_t)n * HD * 4);
    int* rp    = (int*)alloc((size_t)(n + 1) * 4);
    int* deg   = (int*)alloc((size_t)n * 4);
    int* fillc = (int*)alloc((size_t)n * 4);
    int* ci    = (int*)alloc((size_t)e * 4);
    int* bsum  = (int*)alloc(512);
    int* gs    = (int*)alloc((size_t)ngraph * 4);
    int* ge    = (int*)alloc((size_t)ngraph * 4);
    short* wh  = (short*)alloc((size_t)L * 2 * 16384 * 2);
    short* wl  = (short*)alloc((size_t)L * 2 * 16384 * 2);

    hipMemsetAsync(deg,   0, (size_t)n * 4, stream);
    hipMemsetAsync(fillc, 0, (size_t)n * 4, stream);
    hipMemsetAsync(gs,    0, (size_t)ngraph * 4, stream);
    hipMemsetAsync(ge,    0, (size_t)ngraph * 4, stream);

    k_embed<<<(n * 32 + 255) / 256, 256, 0, stream>>>(tok, emb, xa, n);

    int wtot = L * 2 * 16384;
    k_wsplit<<<(wtot + 255) / 256, 256, 0, stream>>>(W1, W2, wh, wl, wtot);

    k_degree<<<(e + 255) / 256, 256, 0, stream>>>(dst, deg, e);
    int nb = (n + 1023) / 1024;
    k_scan1<<<nb, 1024, 0, stream>>>(deg, rp, bsum, n);
    k_scan2<<<1, 128, 0, stream>>>(bsum, nb);
    k_scan3<<<nb, 1024, 0, stream>>>(rp, bsum, n, e);
    k_fill<<<(e + 255) / 256, 256, 0, stream>>>(src, dst, rp, fillc, ci, e);

    float* xin = xa;
    float* xo  = xb;
    for (int l = 0; l < L; ++l) {
        const short* lw = wh + (size_t)l * 2 * 16384;
        const short* ll = wl + (size_t)l * 2 * 16384;
        k_gin<<<(n + TM - 1) / TM, 256, 0, stream>>>(
            xin, xo, rp, ci,
            lw, ll, lw + 16384, ll + 16384,
            b1 + (size_t)l * HD, b2 + (size_t)l * HD, n);
        float* t = xin; xin = xo; xo = t;
    }

    k_ranges<<<(n + 255) / 256, 256, 0, stream>>>(batch, gs, ge, n);
    k_pool<<<ngraph, HD, 0, stream>>>(xin, gs, ge, out);
}

// Round 5
// 772.226 us; speedup vs baseline: 1.1490x; 1.1490x over previous
//
#include <hip/hip_runtime.h>

#define HD  128   // hidden dim
#define TM  64    // node rows per block in the MLP kernel
#define SYB 136   // bf16 LDS stride for H tiles

typedef __attribute__((ext_vector_type(8))) short short8;
typedef __attribute__((ext_vector_type(4))) float float4v;

// split fp32 -> bf16 hi + bf16 lo (RNE both), v == hi + lo to ~2^-17 rel
__device__ __forceinline__ void split_bf(float v, short& hi, short& lo) {
    unsigned bv = __float_as_uint(v);
    unsigned hb = (bv + 0x7FFFu + ((bv >> 16) & 1u)) & 0xFFFF0000u;
    hi = (short)(hb >> 16);
    float r = v - __uint_as_float(hb);
    unsigned rv = __float_as_uint(r);
    lo = (short)((rv + 0x7FFFu + ((rv >> 16) & 1u)) >> 16);
}

// ---------------------------------------------------------------- embed ----
__global__ void k_embed(const int* __restrict__ tok, const float* __restrict__ emb,
                        float* __restrict__ x, int n)
{
    int g = blockIdx.x * 256 + threadIdx.x;
    if (g < n * 32) {
        int node = g >> 5, part = g & 31;
        ((float4*)x)[g] = ((const float4*)emb)[(tok[node] << 5) + part];
    }
}

// ------------------------------------------------------------- CSR build ----
__global__ void k_degree(const int* __restrict__ dst, int* __restrict__ deg, int e)
{
    int i = blockIdx.x * 256 + threadIdx.x;
    if (i < e) atomicAdd(&deg[dst[i]], 1);
}

__global__ void k_scan1(const int* __restrict__ deg, int* __restrict__ rp,
                        int* __restrict__ bsum, int n)
{
    __shared__ int s[1024];
    int t = threadIdx.x;
    int i = blockIdx.x * 1024 + t;
    int v = (i < n) ? deg[i] : 0;
    s[t] = v; __syncthreads();
    for (int off = 1; off < 1024; off <<= 1) {
        int tmp = (t >= off) ? s[t - off] : 0;
        __syncthreads();
        s[t] += tmp;
        __syncthreads();
    }
    if (i < n) rp[i] = s[t] - v;
    if (t == 1023) bsum[blockIdx.x] = s[1023];
}

__global__ void k_scan2(int* __restrict__ bsum, int nb)
{
    __shared__ int s[128];
    int t = threadIdx.x;
    int v = (t < nb) ? bsum[t] : 0;
    s[t] = v; __syncthreads();
    for (int off = 1; off < 128; off <<= 1) {
        int tmp = (t >= off) ? s[t - off] : 0;
        __syncthreads();
        s[t] += tmp;
        __syncthreads();
    }
    if (t < nb) bsum[t] = s[t] - v;
}

__global__ void k_scan3(int* __restrict__ rp, const int* __restrict__ bsum, int n, int e)
{
    int i = blockIdx.x * 1024 + threadIdx.x;
    if (i < n) rp[i] += bsum[blockIdx.x];
    if (i == 0) rp[n] = e;
}

__global__ void k_fill(const int* __restrict__ src, const int* __restrict__ dst,
                       const int* __restrict__ rp, int* __restrict__ fill,
                       int* __restrict__ ci, int e)
{
    int i = blockIdx.x * 256 + threadIdx.x;
    if (i < e) {
        int d = dst[i];
        int p = atomicAdd(&fill[d], 1);
        ci[rp[d] + p] = src[i];
    }
}

// --------------------------------------------- weight split into B-frags ----
// frag idx f = ((ct*4 + kb)*64 + lane)*8 + j holds
// W[kb*32 + (lane>>4)*8 + j][ct*16 + (lane&15)]  (B-operand of 16x16x32)
__global__ void k_wsplit(const float* __restrict__ W1, const float* __restrict__ W2,
                         short* __restrict__ wh, short* __restrict__ wl, int total)
{
    int g = blockIdx.x * 256 + threadIdx.x;
    if (g >= total) return;
    int f  = g & 16383;
    int m  = (g >> 14) & 1;
    int l  = g >> 15;
    int j    = f & 7;
    int lane = (f >> 3) & 63;
    int kb   = (f >> 9) & 3;
    int ct   = f >> 11;
    int k  = kb * 32 + (lane >> 4) * 8 + j;
    int nn = ct * 16 + (lane & 15);
    const float* W = m ? W2 : W1;
    float v = W[(size_t)l * 16384 + k * 128 + nn];
    short h, lo; split_bf(v, h, lo);
    wh[g] = h; wl[g] = lo;
}

// ----------------------------------------------------------- aggregation ----
// thread = (node, part). part covers k = {q*32 + part*4 .. +3 : q<4} so that
// each vmem instruction (fixed q) is 128B-contiguous per node.
// Y written as bf16 hi/lo, row-major k.
__global__ __launch_bounds__(256, 8)
void k_agg(const float* __restrict__ x, const int* __restrict__ rp,
           const int* __restrict__ ci,
           short* __restrict__ yh, short* __restrict__ yl, int n)
{
    int g = blockIdx.x * 256 + threadIdx.x;
    int node = g >> 3, part = g & 7;
    if (node >= n) return;
    const float4* xr = (const float4*)(x + (size_t)node * HD) + part;
    float4 acc[4];
#pragma unroll
    for (int q = 0; q < 4; ++q) acc[q] = xr[q * 8];
    const int e0 = rp[node], e1 = rp[node + 1];
    for (int e = e0; e < e1; ++e) {
        const float4* xc = (const float4*)(x + (size_t)ci[e] * HD) + part;
#pragma unroll
        for (int q = 0; q < 4; ++q) {
            float4 v = xc[q * 8];
            acc[q].x += v.x; acc[q].y += v.y; acc[q].z += v.z; acc[q].w += v.w;
        }
    }
    size_t base = (size_t)node * HD + part * 4;
#pragma unroll
    for (int q = 0; q < 4; ++q) {
        short4 h4, l4;
        split_bf(acc[q].x, h4.x, l4.x);
        split_bf(acc[q].y, h4.y, l4.y);
        split_bf(acc[q].z, h4.z, l4.z);
        split_bf(acc[q].w, h4.w, l4.w);
        *(short4*)(yh + base + q * 32) = h4;
        *(short4*)(yl + base + q * 32) = l4;
    }
}

// ------------------------------------------------------------------- MLP ----
__global__ __launch_bounds__(256, 2)
void k_mlp(const short* __restrict__ yh, const short* __restrict__ yl,
           float* __restrict__ xout,
           const short* __restrict__ w1h, const short* __restrict__ w1l,
           const short* __restrict__ w2h, const short* __restrict__ w2l,
           const float* __restrict__ b1, const float* __restrict__ b2,
           int n)
{
    __shared__ short sHh[TM * SYB];
    __shared__ short sHl[TM * SYB];

    const int tx   = threadIdx.x;
    const int row0 = blockIdx.x * TM;
    const int wv   = tx >> 6, lane = tx & 63;
    const int quad = lane >> 4, lrow = lane & 15;

    // ---- GEMM1: H = relu(Y @ W1 + b1); A-frags straight from global Y
    short8 Bh[2][4];
    {
        const short8* h8 = (const short8*)w1h;
#pragma unroll
        for (int c = 0; c < 2; ++c)
#pragma unroll
            for (int kb = 0; kb < 4; ++kb)
                Bh[c][kb] = h8[((2 * wv + c) * 4 + kb) * 64 + lane];
    }
    float bb0 = b1[(2 * wv + 0) * 16 + lrow];
    float bb1 = b1[(2 * wv + 1) * 16 + lrow];

    float4v acc1[4][2];
#pragma unroll
    for (int rt = 0; rt < 4; ++rt) {
        acc1[rt][0] = (float4v){bb0, bb0, bb0, bb0};
        acc1[rt][1] = (float4v){bb1, bb1, bb1, bb1};
    }

    {
        const short8* l8 = (const short8*)w1l;
#pragma unroll
        for (int kb = 0; kb < 4; ++kb) {
            short8 Ah[4], Al[4];
#pragma unroll
            for (int rt = 0; rt < 4; ++rt) {
                size_t base = (size_t)(row0 + rt * 16 + lrow) * HD + kb * 32 + quad * 8;
                Ah[rt] = *(const short8*)(yh + base);
                Al[rt] = *(const short8*)(yl + base);
            }
            short8 Bl0 = l8[((2 * wv + 0) * 4 + kb) * 64 + lane];
            short8 Bl1 = l8[((2 * wv + 1) * 4 + kb) * 64 + lane];
#pragma unroll
            for (int rt = 0; rt < 4; ++rt) {
                acc1[rt][0] = __builtin_amdgcn_mfma_f32_16x16x32_bf16(Ah[rt], Bh[0][kb], acc1[rt][0], 0, 0, 0);
                acc1[rt][0] = __builtin_amdgcn_mfma_f32_16x16x32_bf16(Al[rt], Bh[0][kb], acc1[rt][0], 0, 0, 0);
                acc1[rt][0] = __builtin_amdgcn_mfma_f32_16x16x32_bf16(Ah[rt], Bl0,       acc1[rt][0], 0, 0, 0);
                acc1[rt][1] = __builtin_amdgcn_mfma_f32_16x16x32_bf16(Ah[rt], Bh[1][kb], acc1[rt][1], 0, 0, 0);
                acc1[rt][1] = __builtin_amdgcn_mfma_f32_16x16x32_bf16(Al[rt], Bh[1][kb], acc1[rt][1], 0, 0, 0);
                acc1[rt][1] = __builtin_amdgcn_mfma_f32_16x16x32_bf16(Ah[rt], Bl1,       acc1[rt][1], 0, 0, 0);
            }
        }
    }

    // H (relu) -> split into sHh/sHl
#pragma unroll
    for (int rt = 0; rt < 4; ++rt)
#pragma unroll
        for (int c = 0; c < 2; ++c) {
            int col = (2 * wv + c) * 16 + lrow;
#pragma unroll
            for (int r = 0; r < 4; ++r) {
                int row = rt * 16 + quad * 4 + r;
                float v = fmaxf(acc1[rt][c][r], 0.f);
                short h, l; split_bf(v, h, l);
                sHh[row * SYB + col] = h;
                sHl[row * SYB + col] = l;
            }
        }

    // GEMM2 B-hi frags + bias (loads overlap the barrier)
    short8 Bh2[2][4];
    {
        const short8* h8 = (const short8*)w2h;
#pragma unroll
        for (int c = 0; c < 2; ++c)
#pragma unroll
            for (int kb = 0; kb < 4; ++kb)
                Bh2[c][kb] = h8[((2 * wv + c) * 4 + kb) * 64 + lane];
    }
    float cb0 = b2[(2 * wv + 0) * 16 + lrow];
    float cb1 = b2[(2 * wv + 1) * 16 + lrow];
    __syncthreads();

    // ---- GEMM2: X' = relu(H @ W2 + b2); A-frags from LDS
    float4v acc2[4][2];
#pragma unroll
    for (int rt = 0; rt < 4; ++rt) {
        acc2[rt][0] = (float4v){cb0, cb0, cb0, cb0};
        acc2[rt][1] = (float4v){cb1, cb1, cb1, cb1};
    }

    {
        const short8* l8 = (const short8*)w2l;
#pragma unroll
        for (int kb = 0; kb < 4; ++kb) {
            short8 Ah[4], Al[4];
#pragma unroll
            for (int rt = 0; rt < 4; ++rt) {
                int off = (rt * 16 + lrow) * SYB + kb * 32 + quad * 8;
                Ah[rt] = *(const short8*)&sHh[off];
                Al[rt] = *(const short8*)&sHl[off];
            }
            short8 Bl0 = l8[((2 * wv + 0) * 4 + kb) * 64 + lane];
            short8 Bl1 = l8[((2 * wv + 1) * 4 + kb) * 64 + lane];
#pragma unroll
            for (int rt = 0; rt < 4; ++rt) {
                acc2[rt][0] = __builtin_amdgcn_mfma_f32_16x16x32_bf16(Ah[rt], Bh2[0][kb], acc2[rt][0], 0, 0, 0);
                acc2[rt][0] = __builtin_amdgcn_mfma_f32_16x16x32_bf16(Al[rt], Bh2[0][kb], acc2[rt][0], 0, 0, 0);
                acc2[rt][0] = __builtin_amdgcn_mfma_f32_16x16x32_bf16(Ah[rt], Bl0,        acc2[rt][0], 0, 0, 0);
                acc2[rt][1] = __builtin_amdgcn_mfma_f32_16x16x32_bf16(Ah[rt], Bh2[1][kb], acc2[rt][1], 0, 0, 0);
                acc2[rt][1] = __builtin_amdgcn_mfma_f32_16x16x32_bf16(Al[rt], Bh2[1][kb], acc2[rt][1], 0, 0, 0);
                acc2[rt][1] = __builtin_amdgcn_mfma_f32_16x16x32_bf16(Ah[rt], Bl1,        acc2[rt][1], 0, 0, 0);
            }
        }
    }

    // epilogue: relu + store fp32 x (in place)
#pragma unroll
    for (int rt = 0; rt < 4; ++rt)
#pragma unroll
        for (int c = 0; c < 2; ++c) {
            int col = (2 * wv + c) * 16 + lrow;
#pragma unroll
            for (int r = 0; r < 4; ++r) {
                int node = row0 + rt * 16 + quad * 4 + r;
                if (node < n)
                    xout[(size_t)node * HD + col] = fmaxf(acc2[rt][c][r], 0.f);
            }
        }
}

// ------------------------------------------------------------------ pool ----
__global__ void k_ranges(const int* __restrict__ batch, int* __restrict__ gs,
                         int* __restrict__ ge, int n)
{
    int i = blockIdx.x * 256 + threadIdx.x;
    if (i < n) {
        int b = batch[i];
        if (i == 0 || batch[i - 1] != b) gs[b] = i;
        if (i == n - 1 || batch[i + 1] != b) ge[b] = i + 1;
    }
}

__global__ void k_pool(const float* __restrict__ x, const int* __restrict__ gs,
                       const int* __restrict__ ge, float* __restrict__ out)
{
    int g = blockIdx.x, t = threadIdx.x;
    int s = gs[g], e = ge[g];
    float sum = 0.f;
    for (int i = s; i < e; ++i) sum += x[(size_t)i * HD + t];
    int cnt = e - s;
    out[(size_t)g * HD + t] = (cnt > 0) ? sum / (float)cnt : 0.f;
}

// ---------------------------------------------------------------- launch ----
extern "C" void kernel_launch(void* const* d_in, const int* in_sizes, int n_in,
                              void* d_out, int out_size, void* d_ws, size_t ws_size,
                              hipStream_t stream)
{
    const int*   tok   = (const int*)d_in[0];
    const int*   eidx  = (const int*)d_in[1];
    const int*   batch = (const int*)d_in[2];
    const float* emb   = (const float*)d_in[3];
    const float* W1    = (const float*)d_in[4];
    const float* b1    = (const float*)d_in[5];
    const float* W2    = (const float*)d_in[6];
    const float* b2    = (const float*)d_in[7];
    float* out = (float*)d_out;

    const int n      = in_sizes[0];
    const int e      = in_sizes[1] / 2;
    const int ngraph = out_size / HD;
    const int L      = in_sizes[4] / (HD * HD);
    const int* src = eidx;
    const int* dst = eidx + e;

    char* w = (char*)d_ws;
    size_t off = 0;
    auto alloc = [&](size_t bytes) -> void* {
        void* p = w + off;
        off = (off + bytes + 255) & ~(size_t)255;
        return p;
    };
    float* xa  = (float*)alloc((size_t)n * HD * 4);
    short* yh  = (short*)alloc((size_t)(n + TM) * HD * 2);   // +TM rows pad for tile OOB reads
    short* yl  = (short*)alloc((size_t)(n + TM) * HD * 2);
    int* rp    = (int*)alloc((size_t)(n + 1) * 4);
    int* deg   = (int*)alloc((size_t)n * 4);
    int* fillc = (int*)alloc((size_t)n * 4);
    int* ci    = (int*)alloc((size_t)e * 4);
    int* bsum  = (int*)alloc(512);
    int* gs    = (int*)alloc((size_t)ngraph * 4);
    int* ge    = (int*)alloc((size_t)ngraph * 4);
    short* wh  = (short*)alloc((size_t)L * 2 * 16384 * 2);
    short* wl  = (short*)alloc((size_t)L * 2 * 16384 * 2);

    hipMemsetAsync(deg,   0, (size_t)n * 4, stream);
    hipMemsetAsync(fillc, 0, (size_t)n * 4, stream);
    hipMemsetAsync(gs,    0, (size_t)ngraph * 4, stream);
    hipMemsetAsync(ge,    0, (size_t)ngraph * 4, stream);

    k_embed<<<(n * 32 + 255) / 256, 256, 0, stream>>>(tok, emb, xa, n);

    int wtot = L * 2 * 16384;
    k_wsplit<<<(wtot + 255) / 256, 256, 0, stream>>>(W1, W2, wh, wl, wtot);

    k_degree<<<(e + 255) / 256, 256, 0, stream>>>(dst, deg, e);
    int nb = (n + 1023) / 1024;
    k_scan1<<<nb, 1024, 0, stream>>>(deg, rp, bsum, n);
    k_scan2<<<1, 128, 0, stream>>>(bsum, nb);
    k_scan3<<<nb, 1024, 0, stream>>>(rp, bsum, n, e);
    k_fill<<<(e + 255) / 256, 256, 0, stream>>>(src, dst, rp, fillc, ci, e);

    for (int l = 0; l < L; ++l) {
        const short* lw = wh + (size_t)l * 2 * 16384;
        const short* ll = wl + (size_t)l * 2 * 16384;
        k_agg<<<(n * 8 + 255) / 256, 256, 0, stream>>>(xa, rp, ci, yh, yl, n);
        k_mlp<<<(n + TM - 1) / TM, 256, 0, stream>>>(
            yh, yl, xa,
            lw, ll, lw + 16384, ll + 16384,
            b1 + (size_t)l * HD, b2 + (size_t)l * HD, n);
    }

    k_ranges<<<(n + 255) / 256, 256, 0, stream>>>(batch, gs, ge, n);
    k_pool<<<ngraph, HD, 0, stream>>>(xa, gs, ge, out);
}

// Round 6
// 698.122 us; speedup vs baseline: 1.2710x; 1.1061x over previous
//
#include <hip/hip_runtime.h>

#define HD  128   // hidden dim
#define TM  64    // node rows per block in the MLP kernel
#define SYB 136   // bf16 LDS stride for Y/H tiles (272 B row: 2-way bank max on b128 reads)

typedef __attribute__((ext_vector_type(8))) short short8;
typedef __attribute__((ext_vector_type(4))) float float4v;

// split fp32 -> bf16 hi + bf16 lo (RNE both), v == hi + lo to ~2^-17 rel
__device__ __forceinline__ void split_bf(float v, short& hi, short& lo) {
    unsigned bv = __float_as_uint(v);
    unsigned hb = (bv + 0x7FFFu + ((bv >> 16) & 1u)) & 0xFFFF0000u;
    hi = (short)(hb >> 16);
    float r = v - __uint_as_float(hb);
    unsigned rv = __float_as_uint(r);
    lo = (short)((rv + 0x7FFFu + ((rv >> 16) & 1u)) >> 16);
}

// ---------------------------------------------------------------- embed ----
__global__ void k_embed(const int* __restrict__ tok, const float* __restrict__ emb,
                        float* __restrict__ x, int n)
{
    int g = blockIdx.x * 256 + threadIdx.x;
    if (g < n * 32) {
        int node = g >> 5, part = g & 31;
        ((float4*)x)[g] = ((const float4*)emb)[(tok[node] << 5) + part];
    }
}

// ------------------------------------------------------------- CSR build ----
__global__ void k_degree(const int* __restrict__ dst, int* __restrict__ deg, int e)
{
    int i = blockIdx.x * 256 + threadIdx.x;
    if (i < e) atomicAdd(&deg[dst[i]], 1);
}

__global__ void k_scan1(const int* __restrict__ deg, int* __restrict__ rp,
                        int* __restrict__ bsum, int n)
{
    __shared__ int s[1024];
    int t = threadIdx.x;
    int i = blockIdx.x * 1024 + t;
    int v = (i < n) ? deg[i] : 0;
    s[t] = v; __syncthreads();
    for (int off = 1; off < 1024; off <<= 1) {
        int tmp = (t >= off) ? s[t - off] : 0;
        __syncthreads();
        s[t] += tmp;
        __syncthreads();
    }
    if (i < n) rp[i] = s[t] - v;
    if (t == 1023) bsum[blockIdx.x] = s[1023];
}

__global__ void k_scan2(int* __restrict__ bsum, int nb)
{
    __shared__ int s[128];
    int t = threadIdx.x;
    int v = (t < nb) ? bsum[t] : 0;
    s[t] = v; __syncthreads();
    for (int off = 1; off < 128; off <<= 1) {
        int tmp = (t >= off) ? s[t - off] : 0;
        __syncthreads();
        s[t] += tmp;
        __syncthreads();
    }
    if (t < nb) bsum[t] = s[t] - v;
}

__global__ void k_scan3(int* __restrict__ rp, const int* __restrict__ bsum, int n, int e)
{
    int i = blockIdx.x * 1024 + threadIdx.x;
    if (i < n) rp[i] += bsum[blockIdx.x];
    if (i == 0) rp[n] = e;
}

__global__ void k_fill(const int* __restrict__ src, const int* __restrict__ dst,
                       const int* __restrict__ rp, int* __restrict__ fill,
                       int* __restrict__ ci, int e)
{
    int i = blockIdx.x * 256 + threadIdx.x;
    if (i < e) {
        int d = dst[i];
        int p = atomicAdd(&fill[d], 1);
        ci[rp[d] + p] = src[i];
    }
}

// --------------------------------------------- weight split into B-frags ----
// frag idx f = ((ct*4 + kb)*64 + lane)*8 + j holds
// W[kb*32 + (lane>>4)*8 + j][ct*16 + (lane&15)]  (B-operand of 16x16x32)
__global__ void k_wsplit(const float* __restrict__ W1, const float* __restrict__ W2,
                         short* __restrict__ wh, short* __restrict__ wl, int total)
{
    int g = blockIdx.x * 256 + threadIdx.x;
    if (g >= total) return;
    int f  = g & 16383;
    int m  = (g >> 14) & 1;
    int l  = g >> 15;
    int j    = f & 7;
    int lane = (f >> 3) & 63;
    int kb   = (f >> 9) & 3;
    int ct   = f >> 11;
    int k  = kb * 32 + (lane >> 4) * 8 + j;
    int nn = ct * 16 + (lane & 15);
    const float* W = m ? W2 : W1;
    float v = W[(size_t)l * 16384 + k * 128 + nn];
    short h, lo; split_bf(v, h, lo);
    wh[g] = h; wl[g] = lo;
}

// ----------------------------------------------------------- aggregation ----
// thread = (node, part). part covers k = {q*32 + part*4 .. +3 : q<4} so that
// each vmem instruction (fixed q) is 128B-contiguous per node.
__global__ __launch_bounds__(256, 8)
void k_agg(const float* __restrict__ x, const int* __restrict__ rp,
           const int* __restrict__ ci,
           short* __restrict__ yh, short* __restrict__ yl, int n)
{
    int g = blockIdx.x * 256 + threadIdx.x;
    int node = g >> 3, part = g & 7;
    if (node >= n) return;
    const float4* xr = (const float4*)(x + (size_t)node * HD) + part;
    float4 acc[4];
#pragma unroll
    for (int q = 0; q < 4; ++q) acc[q] = xr[q * 8];
    const int e0 = rp[node], e1 = rp[node + 1];
    for (int e = e0; e < e1; ++e) {
        const float4* xc = (const float4*)(x + (size_t)ci[e] * HD) + part;
#pragma unroll
        for (int q = 0; q < 4; ++q) {
            float4 v = xc[q * 8];
            acc[q].x += v.x; acc[q].y += v.y; acc[q].z += v.z; acc[q].w += v.w;
        }
    }
    size_t base = (size_t)node * HD + part * 4;
#pragma unroll
    for (int q = 0; q < 4; ++q) {
        short4 h4, l4;
        split_bf(acc[q].x, h4.x, l4.x);
        split_bf(acc[q].y, h4.y, l4.y);
        split_bf(acc[q].z, h4.z, l4.z);
        split_bf(acc[q].w, h4.w, l4.w);
        *(short4*)(yh + base + q * 32) = h4;
        *(short4*)(yl + base + q * 32) = l4;
    }
}

// ------------------------------------------------------------------- MLP ----
__global__ __launch_bounds__(256, 2)
void k_mlp(const short* __restrict__ yh, const short* __restrict__ yl,
           float* __restrict__ xout,
           const short* __restrict__ w1h, const short* __restrict__ w1l,
           const short* __restrict__ w2h, const short* __restrict__ w2l,
           const float* __restrict__ b1, const float* __restrict__ b2,
           int n)
{
    __shared__ short sAh[TM * SYB];   // Y tile, then H tile (hi)
    __shared__ short sAl[TM * SYB];   // (lo)

    const int tx   = threadIdx.x;
    const int row0 = blockIdx.x * TM;
    const int wv   = tx >> 6, lane = tx & 63;
    const int quad = lane >> 4, lrow = lane & 15;

    // B1 hi frags + bias (global, L2-hot)
    short8 Bh[2][4];
    {
        const short8* h8 = (const short8*)w1h;
#pragma unroll
        for (int c = 0; c < 2; ++c)
#pragma unroll
            for (int kb = 0; kb < 4; ++kb)
                Bh[c][kb] = h8[((2 * wv + c) * 4 + kb) * 64 + lane];
    }
    float bb0 = b1[(2 * wv + 0) * 16 + lrow];
    float bb1 = b1[(2 * wv + 1) * 16 + lrow];

    // ---- stage Y tile (hi+lo) into LDS, coalesced: chunk = short8, 16/row
    {
        const short8* gh = (const short8*)(yh + (size_t)row0 * HD);
        const short8* gl = (const short8*)(yl + (size_t)row0 * HD);
#pragma unroll
        for (int i = 0; i < 4; ++i) {
            int idx  = i * 256 + tx;            // 0..1023
            int row  = idx >> 4, col8 = idx & 15;
            short8 vh = gh[idx];
            short8 vl = gl[idx];
            *(short8*)&sAh[row * SYB + col8 * 8] = vh;
            *(short8*)&sAl[row * SYB + col8 * 8] = vl;
        }
    }
    __syncthreads();

    // ---- GEMM1: H = relu(Y @ W1 + b1)
    float4v acc1[4][2];
#pragma unroll
    for (int rt = 0; rt < 4; ++rt) {
        acc1[rt][0] = (float4v){bb0, bb0, bb0, bb0};
        acc1[rt][1] = (float4v){bb1, bb1, bb1, bb1};
    }

    {
        const short8* l8 = (const short8*)w1l;
#pragma unroll
        for (int kb = 0; kb < 4; ++kb) {
            short8 Ah[4], Al[4];
#pragma unroll
            for (int rt = 0; rt < 4; ++rt) {
                int off = (rt * 16 + lrow) * SYB + kb * 32 + quad * 8;
                Ah[rt] = *(const short8*)&sAh[off];
                Al[rt] = *(const short8*)&sAl[off];
            }
            short8 Bl0 = l8[((2 * wv + 0) * 4 + kb) * 64 + lane];
            short8 Bl1 = l8[((2 * wv + 1) * 4 + kb) * 64 + lane];
#pragma unroll
            for (int rt = 0; rt < 4; ++rt) {
                acc1[rt][0] = __builtin_amdgcn_mfma_f32_16x16x32_bf16(Ah[rt], Bh[0][kb], acc1[rt][0], 0, 0, 0);
                acc1[rt][0] = __builtin_amdgcn_mfma_f32_16x16x32_bf16(Al[rt], Bh[0][kb], acc1[rt][0], 0, 0, 0);
                acc1[rt][0] = __builtin_amdgcn_mfma_f32_16x16x32_bf16(Ah[rt], Bl0,       acc1[rt][0], 0, 0, 0);
                acc1[rt][1] = __builtin_amdgcn_mfma_f32_16x16x32_bf16(Ah[rt], Bh[1][kb], acc1[rt][1], 0, 0, 0);
                acc1[rt][1] = __builtin_amdgcn_mfma_f32_16x16x32_bf16(Al[rt], Bh[1][kb], acc1[rt][1], 0, 0, 0);
                acc1[rt][1] = __builtin_amdgcn_mfma_f32_16x16x32_bf16(Ah[rt], Bl1,       acc1[rt][1], 0, 0, 0);
            }
        }
    }

    // B2 hi frags + bias (loads issued before barrier, overlap it)
    short8 Bh2[2][4];
    {
        const short8* h8 = (const short8*)w2h;
#pragma unroll
        for (int c = 0; c < 2; ++c)
#pragma unroll
            for (int kb = 0; kb < 4; ++kb)
                Bh2[c][kb] = h8[((2 * wv + c) * 4 + kb) * 64 + lane];
    }
    float cb0 = b2[(2 * wv + 0) * 16 + lrow];
    float cb1 = b2[(2 * wv + 1) * 16 + lrow];

    __syncthreads();   // all waves done reading Y from LDS

    // H (relu) -> split into sAh/sAl (overwrite Y)
#pragma unroll
    for (int rt = 0; rt < 4; ++rt)
#pragma unroll
        for (int c = 0; c < 2; ++c) {
            int col = (2 * wv + c) * 16 + lrow;
#pragma unroll
            for (int r = 0; r < 4; ++r) {
                int row = rt * 16 + quad * 4 + r;
                float v = fmaxf(acc1[rt][c][r], 0.f);
                short h, l; split_bf(v, h, l);
                sAh[row * SYB + col] = h;
                sAl[row * SYB + col] = l;
            }
        }
    __syncthreads();

    // ---- GEMM2: X' = relu(H @ W2 + b2)
    float4v acc2[4][2];
#pragma unroll
    for (int rt = 0; rt < 4; ++rt) {
        acc2[rt][0] = (float4v){cb0, cb0, cb0, cb0};
        acc2[rt][1] = (float4v){cb1, cb1, cb1, cb1};
    }

    {
        const short8* l8 = (const short8*)w2l;
#pragma unroll
        for (int kb = 0; kb < 4; ++kb) {
            short8 Ah[4], Al[4];
#pragma unroll
            for (int rt = 0; rt < 4; ++rt) {
                int off = (rt * 16 + lrow) * SYB + kb * 32 + quad * 8;
                Ah[rt] = *(const short8*)&sAh[off];
                Al[rt] = *(const short8*)&sAl[off];
            }
            short8 Bl0 = l8[((2 * wv + 0) * 4 + kb) * 64 + lane];
            short8 Bl1 = l8[((2 * wv + 1) * 4 + kb) * 64 + lane];
#pragma unroll
            for (int rt = 0; rt < 4; ++rt) {
                acc2[rt][0] = __builtin_amdgcn_mfma_f32_16x16x32_bf16(Ah[rt], Bh2[0][kb], acc2[rt][0], 0, 0, 0);
                acc2[rt][0] = __builtin_amdgcn_mfma_f32_16x16x32_bf16(Al[rt], Bh2[0][kb], acc2[rt][0], 0, 0, 0);
                acc2[rt][0] = __builtin_amdgcn_mfma_f32_16x16x32_bf16(Ah[rt], Bl0,        acc2[rt][0], 0, 0, 0);
                acc2[rt][1] = __builtin_amdgcn_mfma_f32_16x16x32_bf16(Ah[rt], Bh2[1][kb], acc2[rt][1], 0, 0, 0);
                acc2[rt][1] = __builtin_amdgcn_mfma_f32_16x16x32_bf16(Al[rt], Bh2[1][kb], acc2[rt][1], 0, 0, 0);
                acc2[rt][1] = __builtin_amdgcn_mfma_f32_16x16x32_bf16(Ah[rt], Bl1,        acc2[rt][1], 0, 0, 0);
            }
        }
    }

    // epilogue: relu + store fp32 x (in place)
#pragma unroll
    for (int rt = 0; rt < 4; ++rt)
#pragma unroll
        for (int c = 0; c < 2; ++c) {
            int col = (2 * wv + c) * 16 + lrow;
#pragma unroll
            for (int r = 0; r < 4; ++r) {
                int node = row0 + rt * 16 + quad * 4 + r;
                if (node < n)
                    xout[(size_t)node * HD + col] = fmaxf(acc2[rt][c][r], 0.f);
            }
        }
}

// ------------------------------------------------------------------ pool ----
__global__ void k_ranges(const int* __restrict__ batch, int* __restrict__ gs,
                         int* __restrict__ ge, int n)
{
    int i = blockIdx.x * 256 + threadIdx.x;
    if (i < n) {
        int b = batch[i];
        if (i == 0 || batch[i - 1] != b) gs[b] = i;
        if (i == n - 1 || batch[i + 1] != b) ge[b] = i + 1;
    }
}

__global__ void k_pool(const float* __restrict__ x, const int* __restrict__ gs,
                       const int* __restrict__ ge, float* __restrict__ out)
{
    int g = blockIdx.x, t = threadIdx.x;
    int s = gs[g], e = ge[g];
    float sum = 0.f;
    for (int i = s; i < e; ++i) sum += x[(size_t)i * HD + t];
    int cnt = e - s;
    out[(size_t)g * HD + t] = (cnt > 0) ? sum / (float)cnt : 0.f;
}

// ---------------------------------------------------------------- launch ----
extern "C" void kernel_launch(void* const* d_in, const int* in_sizes, int n_in,
                              void* d_out, int out_size, void* d_ws, size_t ws_size,
                              hipStream_t stream)
{
    const int*   tok   = (const int*)d_in[0];
    const int*   eidx  = (const int*)d_in[1];
    const int*   batch = (const int*)d_in[2];
    const float* emb   = (const float*)d_in[3];
    const float* W1    = (const float*)d_in[4];
    const float* b1    = (const float*)d_in[5];
    const float* W2    = (const float*)d_in[6];
    const float* b2    = (const float*)d_in[7];
    float* out = (float*)d_out;

    const int n      = in_sizes[0];
    const int e      = in_sizes[1] / 2;
    const int ngraph = out_size / HD;
    const int L      = in_sizes[4] / (HD * HD);
    const int* src = eidx;
    const int* dst = eidx + e;

    char* w = (char*)d_ws;
    size_t off = 0;
    auto alloc = [&](size_t bytes) -> void* {
        void* p = w + off;
        off = (off + bytes + 255) & ~(size_t)255;
        return p;
    };
    float* xa  = (float*)alloc((size_t)n * HD * 4);
    short* yh  = (short*)alloc((size_t)(n + TM) * HD * 2);   // +TM rows pad for tile OOB reads
    short* yl  = (short*)alloc((size_t)(n + TM) * HD * 2);
    int* rp    = (int*)alloc((size_t)(n + 1) * 4);
    int* deg   = (int*)alloc((size_t)n * 4);
    int* fillc = (int*)alloc((size_t)n * 4);
    int* ci    = (int*)alloc((size_t)e * 4);
    int* bsum  = (int*)alloc(512);
    int* gs    = (int*)alloc((size_t)ngraph * 4);
    int* ge    = (int*)alloc((size_t)ngraph * 4);
    short* wh  = (short*)alloc((size_t)L * 2 * 16384 * 2);
    short* wl  = (short*)alloc((size_t)L * 2 * 16384 * 2);

    hipMemsetAsync(deg,   0, (size_t)n * 4, stream);
    hipMemsetAsync(fillc, 0, (size_t)n * 4, stream);
    hipMemsetAsync(gs,    0, (size_t)ngraph * 4, stream);
    hipMemsetAsync(ge,    0, (size_t)ngraph * 4, stream);

    k_embed<<<(n * 32 + 255) / 256, 256, 0, stream>>>(tok, emb, xa, n);

    int wtot = L * 2 * 16384;
    k_wsplit<<<(wtot + 255) / 256, 256, 0, stream>>>(W1, W2, wh, wl, wtot);

    k_degree<<<(e + 255) / 256, 256, 0, stream>>>(dst, deg, e);
    int nb = (n + 1023) / 1024;
    k_scan1<<<nb, 1024, 0, stream>>>(deg, rp, bsum, n);
    k_scan2<<<1, 128, 0, stream>>>(bsum, nb);
    k_scan3<<<nb, 1024, 0, stream>>>(rp, bsum, n, e);
    k_fill<<<(e + 255) / 256, 256, 0, stream>>>(src, dst, rp, fillc, ci, e);

    for (int l = 0; l < L; ++l) {
        const short* lw = wh + (size_t)l * 2 * 16384;
        const short* ll = wl + (size_t)l * 2 * 16384;
        k_agg<<<(n * 8 + 255) / 256, 256, 0, stream>>>(xa, rp, ci, yh, yl, n);
        k_mlp<<<(n + TM - 1) / TM, 256, 0, stream>>>(
            yh, yl, xa,
            lw, ll, lw + 16384, ll + 16384,
            b1 + (size_t)l * HD, b2 + (size_t)l * HD, n);
    }

    k_ranges<<<(n + 255) / 256, 256, 0, stream>>>(batch, gs, ge, n);
    k_pool<<<ngraph, HD, 0, stream>>>(xa, gs, ge, out);
}

// Round 7
// 467.997 us; speedup vs baseline: 1.8960x; 1.4917x over previous
//
#include <hip/hip_runtime.h>

#define HD  128   // hidden dim
#define TM  64    // node rows per block in the GIN layer kernel
#define SYB 136   // bf16 LDS stride for Y/H tiles

typedef __attribute__((ext_vector_type(8))) short    short8;
typedef __attribute__((ext_vector_type(8))) _Float16 half8;
typedef __attribute__((ext_vector_type(4))) float    float4v;

// split fp32 -> bf16 hi + bf16 lo (RNE both), v == hi + lo to ~2^-17 rel
__device__ __forceinline__ void split_bf(float v, short& hi, short& lo) {
    unsigned bv = __float_as_uint(v);
    unsigned hb = (bv + 0x7FFFu + ((bv >> 16) & 1u)) & 0xFFFF0000u;
    hi = (short)(hb >> 16);
    float r = v - __uint_as_float(hb);
    unsigned rv = __float_as_uint(r);
    lo = (short)((rv + 0x7FFFu + ((rv >> 16) & 1u)) >> 16);
}

// ---------------------------------------------------------------- embed ----
// x stored fp16 (one quantization point; also applied per-layer epilogue)
__global__ void k_embed(const int* __restrict__ tok, const float* __restrict__ emb,
                        _Float16* __restrict__ x, int n)
{
    int g = blockIdx.x * 256 + threadIdx.x;      // thread = (node, part<16), 8 elems
    if (g < n * 16) {
        int node = g >> 4, part = g & 15;
        const float4* e4 = (const float4*)emb + ((size_t)tok[node] << 5) + part * 2;
        float4 a = e4[0], b = e4[1];
        half8 h;
        h[0] = (_Float16)a.x; h[1] = (_Float16)a.y; h[2] = (_Float16)a.z; h[3] = (_Float16)a.w;
        h[4] = (_Float16)b.x; h[5] = (_Float16)b.y; h[6] = (_Float16)b.z; h[7] = (_Float16)b.w;
        ((half8*)x)[g] = h;
    }
}

// ------------------------------------------------------------- CSR build ----
__global__ void k_degree(const int* __restrict__ dst, int* __restrict__ deg, int e)
{
    int i = blockIdx.x * 256 + threadIdx.x;
    if (i < e) atomicAdd(&deg[dst[i]], 1);
}

__global__ void k_scan1(const int* __restrict__ deg, int* __restrict__ rp,
                        int* __restrict__ bsum, int n)
{
    __shared__ int s[1024];
    int t = threadIdx.x;
    int i = blockIdx.x * 1024 + t;
    int v = (i < n) ? deg[i] : 0;
    s[t] = v; __syncthreads();
    for (int off = 1; off < 1024; off <<= 1) {
        int tmp = (t >= off) ? s[t - off] : 0;
        __syncthreads();
        s[t] += tmp;
        __syncthreads();
    }
    if (i < n) rp[i] = s[t] - v;
    if (t == 1023) bsum[blockIdx.x] = s[1023];
}

__global__ void k_scan2(int* __restrict__ bsum, int nb)
{
    __shared__ int s[128];
    int t = threadIdx.x;
    int v = (t < nb) ? bsum[t] : 0;
    s[t] = v; __syncthreads();
    for (int off = 1; off < 128; off <<= 1) {
        int tmp = (t >= off) ? s[t - off] : 0;
        __syncthreads();
        s[t] += tmp;
        __syncthreads();
    }
    if (t < nb) bsum[t] = s[t] - v;
}

__global__ void k_scan3(int* __restrict__ rp, const int* __restrict__ bsum, int n, int e)
{
    int i = blockIdx.x * 1024 + threadIdx.x;
    if (i < n) rp[i] += bsum[blockIdx.x];
    if (i == 0) rp[n] = e;
}

__global__ void k_fill(const int* __restrict__ src, const int* __restrict__ dst,
                       const int* __restrict__ rp, int* __restrict__ fill,
                       int* __restrict__ ci, int e)
{
    int i = blockIdx.x * 256 + threadIdx.x;
    if (i < e) {
        int d = dst[i];
        int p = atomicAdd(&fill[d], 1);
        ci[rp[d] + p] = src[i];
    }
}

// --------------------------------------------- weight split into B-frags ----
// frag idx f = ((ct*4 + kb)*64 + lane)*8 + j holds
// W[kb*32 + (lane>>4)*8 + j][ct*16 + (lane&15)]  (B-operand of 16x16x32)
__global__ void k_wsplit(const float* __restrict__ W1, const float* __restrict__ W2,
                         short* __restrict__ wh, short* __restrict__ wl, int total)
{
    int g = blockIdx.x * 256 + threadIdx.x;
    if (g >= total) return;
    int f  = g & 16383;
    int m  = (g >> 14) & 1;
    int l  = g >> 15;
    int j    = f & 7;
    int lane = (f >> 3) & 63;
    int kb   = (f >> 9) & 3;
    int ct   = f >> 11;
    int k  = kb * 32 + (lane >> 4) * 8 + j;
    int nn = ct * 16 + (lane & 15);
    const float* W = m ? W2 : W1;
    float v = W[(size_t)l * 16384 + k * 128 + nn];
    short h, lo; split_bf(v, h, lo);
    wh[g] = h; wl[g] = lo;
}

// ------------------------------------------------------- fused GIN layer ----
__global__ __launch_bounds__(256, 2)
void k_gin(const _Float16* __restrict__ xin, _Float16* __restrict__ xout,
           const int* __restrict__ rp, const int* __restrict__ ci,
           const short* __restrict__ w1h, const short* __restrict__ w1l,
           const short* __restrict__ w2h, const short* __restrict__ w2l,
           const float* __restrict__ b1, const float* __restrict__ b2,
           int n)
{
    __shared__ short sAh[TM * SYB];   // Y tile, then H tile (hi)
    __shared__ short sAl[TM * SYB];   // (lo)

    const int tx   = threadIdx.x;
    const int row0 = blockIdx.x * TM;
    const int wv   = tx >> 6, lane = tx & 63;
    const int quad = lane >> 4, lrow = lane & 15;

    // B1 hi frags + bias first (latency overlaps the gather)
    short8 Bh[2][4];
    {
        const short8* h8 = (const short8*)w1h;
#pragma unroll
        for (int c = 0; c < 2; ++c)
#pragma unroll
            for (int kb = 0; kb < 4; ++kb)
                Bh[c][kb] = h8[((2 * wv + c) * 4 + kb) * 64 + lane];
    }
    float bb0 = b1[(2 * wv + 0) * 16 + lrow];
    float bb1 = b1[(2 * wv + 1) * 16 + lrow];

    // ---- aggregation: Y[row] = x[row] + sum_{j in CSR[row]} x[j] (fp16 in, fp32 acc)
    {
        const int rl = tx >> 2, part = tx & 3;   // 4 threads/row; part covers elems q*32+part*8..+7
        const int node = row0 + rl;
        float acc[4][8];
        if (node < n) {
            const half8* xr = (const half8*)(xin + (size_t)node * HD);
#pragma unroll
            for (int q = 0; q < 4; ++q) {
                half8 v = xr[q * 4 + part];
#pragma unroll
                for (int j = 0; j < 8; ++j) acc[q][j] = (float)v[j];
            }
            const int e0 = rp[node], e1 = rp[node + 1];
            for (int e = e0; e < e1; ++e) {
                const half8* xc = (const half8*)(xin + (size_t)ci[e] * HD);
#pragma unroll
                for (int q = 0; q < 4; ++q) {
                    half8 v = xc[q * 4 + part];
#pragma unroll
                    for (int j = 0; j < 8; ++j) acc[q][j] += (float)v[j];
                }
            }
        } else {
#pragma unroll
            for (int q = 0; q < 4; ++q)
#pragma unroll
                for (int j = 0; j < 8; ++j) acc[q][j] = 0.f;
        }
        // split fp32 -> bf16 hi/lo into LDS
#pragma unroll
        for (int q = 0; q < 4; ++q) {
            short8 h8s, l8s;
#pragma unroll
            for (int j = 0; j < 8; ++j) { short h, l; split_bf(acc[q][j], h, l); h8s[j] = h; l8s[j] = l; }
            int off = rl * SYB + q * 32 + part * 8;
            *(short8*)&sAh[off] = h8s;
            *(short8*)&sAl[off] = l8s;
        }
    }
    __syncthreads();

    // ---- GEMM1: H = relu(Y @ W1 + b1)
    float4v acc1[4][2];
#pragma unroll
    for (int rt = 0; rt < 4; ++rt) {
        acc1[rt][0] = (float4v){bb0, bb0, bb0, bb0};
        acc1[rt][1] = (float4v){bb1, bb1, bb1, bb1};
    }
    {
        const short8* l8 = (const short8*)w1l;
#pragma unroll
        for (int kb = 0; kb < 4; ++kb) {
            short8 Ah[4], Al[4];
#pragma unroll
            for (int rt = 0; rt < 4; ++rt) {
                int off = (rt * 16 + lrow) * SYB + kb * 32 + quad * 8;
                Ah[rt] = *(const short8*)&sAh[off];
                Al[rt] = *(const short8*)&sAl[off];
            }
            short8 Bl0 = l8[((2 * wv + 0) * 4 + kb) * 64 + lane];
            short8 Bl1 = l8[((2 * wv + 1) * 4 + kb) * 64 + lane];
#pragma unroll
            for (int rt = 0; rt < 4; ++rt) {
                acc1[rt][0] = __builtin_amdgcn_mfma_f32_16x16x32_bf16(Ah[rt], Bh[0][kb], acc1[rt][0], 0, 0, 0);
                acc1[rt][0] = __builtin_amdgcn_mfma_f32_16x16x32_bf16(Al[rt], Bh[0][kb], acc1[rt][0], 0, 0, 0);
                acc1[rt][0] = __builtin_amdgcn_mfma_f32_16x16x32_bf16(Ah[rt], Bl0,       acc1[rt][0], 0, 0, 0);
                acc1[rt][1] = __builtin_amdgcn_mfma_f32_16x16x32_bf16(Ah[rt], Bh[1][kb], acc1[rt][1], 0, 0, 0);
                acc1[rt][1] = __builtin_amdgcn_mfma_f32_16x16x32_bf16(Al[rt], Bh[1][kb], acc1[rt][1], 0, 0, 0);
                acc1[rt][1] = __builtin_amdgcn_mfma_f32_16x16x32_bf16(Ah[rt], Bl1,       acc1[rt][1], 0, 0, 0);
            }
        }
    }

    // B2 hi frags + bias (issue before barrier, overlap it)
    short8 Bh2[2][4];
    {
        const short8* h8 = (const short8*)w2h;
#pragma unroll
        for (int c = 0; c < 2; ++c)
#pragma unroll
            for (int kb = 0; kb < 4; ++kb)
                Bh2[c][kb] = h8[((2 * wv + c) * 4 + kb) * 64 + lane];
    }
    float cb0 = b2[(2 * wv + 0) * 16 + lrow];
    float cb1 = b2[(2 * wv + 1) * 16 + lrow];

    __syncthreads();   // all waves done reading Y from LDS

    // H (relu) -> split into sAh/sAl (overwrite Y)
#pragma unroll
    for (int rt = 0; rt < 4; ++rt)
#pragma unroll
        for (int c = 0; c < 2; ++c) {
            int col = (2 * wv + c) * 16 + lrow;
#pragma unroll
            for (int r = 0; r < 4; ++r) {
                int row = rt * 16 + quad * 4 + r;
                float v = fmaxf(acc1[rt][c][r], 0.f);
                short h, l; split_bf(v, h, l);
                sAh[row * SYB + col] = h;
                sAl[row * SYB + col] = l;
            }
        }
    __syncthreads();

    // ---- GEMM2: X' = relu(H @ W2 + b2)
    float4v acc2[4][2];
#pragma unroll
    for (int rt = 0; rt < 4; ++rt) {
        acc2[rt][0] = (float4v){cb0, cb0, cb0, cb0};
        acc2[rt][1] = (float4v){cb1, cb1, cb1, cb1};
    }
    {
        const short8* l8 = (const short8*)w2l;
#pragma unroll
        for (int kb = 0; kb < 4; ++kb) {
            short8 Ah[4], Al[4];
#pragma unroll
            for (int rt = 0; rt < 4; ++rt) {
                int off = (rt * 16 + lrow) * SYB + kb * 32 + quad * 8;
                Ah[rt] = *(const short8*)&sAh[off];
                Al[rt] = *(const short8*)&sAl[off];
            }
            short8 Bl0 = l8[((2 * wv + 0) * 4 + kb) * 64 + lane];
            short8 Bl1 = l8[((2 * wv + 1) * 4 + kb) * 64 + lane];
#pragma unroll
            for (int rt = 0; rt < 4; ++rt) {
                acc2[rt][0] = __builtin_amdgcn_mfma_f32_16x16x32_bf16(Ah[rt], Bh2[0][kb], acc2[rt][0], 0, 0, 0);
                acc2[rt][0] = __builtin_amdgcn_mfma_f32_16x16x32_bf16(Al[rt], Bh2[0][kb], acc2[rt][0], 0, 0, 0);
                acc2[rt][0] = __builtin_amdgcn_mfma_f32_16x16x32_bf16(Ah[rt], Bl0,        acc2[rt][0], 0, 0, 0);
                acc2[rt][1] = __builtin_amdgcn_mfma_f32_16x16x32_bf16(Ah[rt], Bh2[1][kb], acc2[rt][1], 0, 0, 0);
                acc2[rt][1] = __builtin_amdgcn_mfma_f32_16x16x32_bf16(Al[rt], Bh2[1][kb], acc2[rt][1], 0, 0, 0);
                acc2[rt][1] = __builtin_amdgcn_mfma_f32_16x16x32_bf16(Ah[rt], Bl1,        acc2[rt][1], 0, 0, 0);
            }
        }
    }

    // epilogue: relu + store fp16 x (write-combined scalar shorts)
#pragma unroll
    for (int rt = 0; rt < 4; ++rt)
#pragma unroll
        for (int c = 0; c < 2; ++c) {
            int col = (2 * wv + c) * 16 + lrow;
#pragma unroll
            for (int r = 0; r < 4; ++r) {
                int node = row0 + rt * 16 + quad * 4 + r;
                if (node < n)
                    xout[(size_t)node * HD + col] = (_Float16)fmaxf(acc2[rt][c][r], 0.f);
            }
        }
}

// ------------------------------------------------------------------ pool ----
__global__ void k_ranges(const int* __restrict__ batch, int* __restrict__ gs,
                         int* __restrict__ ge, int n)
{
    int i = blockIdx.x * 256 + threadIdx.x;
    if (i < n) {
        int b = batch[i];
        if (i == 0 || batch[i - 1] != b) gs[b] = i;
        if (i == n - 1 || batch[i + 1] != b) ge[b] = i + 1;
    }
}

__global__ void k_pool(const _Float16* __restrict__ x, const int* __restrict__ gs,
                       const int* __restrict__ ge, float* __restrict__ out)
{
    int g = blockIdx.x, t = threadIdx.x;
    int s = gs[g], e = ge[g];
    float sum = 0.f;
    for (int i = s; i < e; ++i) sum += (float)x[(size_t)i * HD + t];
    int cnt = e - s;
    out[(size_t)g * HD + t] = (cnt > 0) ? sum / (float)cnt : 0.f;
}

// ---------------------------------------------------------------- launch ----
extern "C" void kernel_launch(void* const* d_in, const int* in_sizes, int n_in,
                              void* d_out, int out_size, void* d_ws, size_t ws_size,
                              hipStream_t stream)
{
    const int*   tok   = (const int*)d_in[0];
    const int*   eidx  = (const int*)d_in[1];
    const int*   batch = (const int*)d_in[2];
    const float* emb   = (const float*)d_in[3];
    const float* W1    = (const float*)d_in[4];
    const float* b1    = (const float*)d_in[5];
    const float* W2    = (const float*)d_in[6];
    const float* b2    = (const float*)d_in[7];
    float* out = (float*)d_out;

    const int n      = in_sizes[0];
    const int e      = in_sizes[1] / 2;
    const int ngraph = out_size / HD;
    const int L      = in_sizes[4] / (HD * HD);
    const int* src = eidx;
    const int* dst = eidx + e;

    char* w = (char*)d_ws;
    size_t off = 0;
    auto alloc = [&](size_t bytes) -> void* {
        void* p = w + off;
        off = (off + bytes + 255) & ~(size_t)255;
        return p;
    };
    _Float16* xa = (_Float16*)alloc((size_t)(n + TM) * HD * 2);
    _Float16* xb = (_Float16*)alloc((size_t)(n + TM) * HD * 2);
    int* rp    = (int*)alloc((size_t)(n + 1) * 4);
    int* deg   = (int*)alloc((size_t)n * 4);
    int* fillc = (int*)alloc((size_t)n * 4);
    int* ci    = (int*)alloc((size_t)e * 4);
    int* bsum  = (int*)alloc(512);
    int* gs    = (int*)alloc((size_t)ngraph * 4);
    int* ge    = (int*)alloc((size_t)ngraph * 4);
    short* wh  = (short*)alloc((size_t)L * 2 * 16384 * 2);
    short* wl  = (short*)alloc((size_t)L * 2 * 16384 * 2);

    hipMemsetAsync(deg,   0, (size_t)n * 4, stream);
    hipMemsetAsync(fillc, 0, (size_t)n * 4, stream);
    hipMemsetAsync(gs,    0, (size_t)ngraph * 4, stream);
    hipMemsetAsync(ge,    0, (size_t)ngraph * 4, stream);

    k_embed<<<(n * 16 + 255) / 256, 256, 0, stream>>>(tok, emb, xa, n);

    int wtot = L * 2 * 16384;
    k_wsplit<<<(wtot + 255) / 256, 256, 0, stream>>>(W1, W2, wh, wl, wtot);

    k_degree<<<(e + 255) / 256, 256, 0, stream>>>(dst, deg, e);
    int nb = (n + 1023) / 1024;
    k_scan1<<<nb, 1024, 0, stream>>>(deg, rp, bsum, n);
    k_scan2<<<1, 128, 0, stream>>>(bsum, nb);
    k_scan3<<<nb, 1024, 0, stream>>>(rp, bsum, n, e);
    k_fill<<<(e + 255) / 256, 256, 0, stream>>>(src, dst, rp, fillc, ci, e);

    _Float16* xin = xa;
    _Float16* xo  = xb;
    for (int l = 0; l < L; ++l) {
        const short* lw = wh + (size_t)l * 2 * 16384;
        const short* ll = wl + (size_t)l * 2 * 16384;
        k_gin<<<(n + TM - 1) / TM, 256, 0, stream>>>(
            xin, xo, rp, ci,
            lw, ll, lw + 16384, ll + 16384,
            b1 + (size_t)l * HD, b2 + (size_t)l * HD, n);
        _Float16* t = xin; xin = xo; xo = t;
    }

    k_ranges<<<(n + 255) / 256, 256, 0, stream>>>(batch, gs, ge, n);
    k_pool<<<ngraph, HD, 0, stream>>>(xin, gs, ge, out);
}